// Round 1
// baseline (880.883 us; speedup 1.0000x reference)
//
#include <hip/hip_runtime.h>

static constexpr int    kN = 200000;
static constexpr int    kC = 20;
static constexpr int    kP = 256;
static constexpr int    kM = 400000;
static constexpr int    kThreshPts = 100;

// output layout (float elements)
static constexpr size_t OFF_SCORES  = 0;
static constexpr size_t OFF_MASKS   = 256;
static constexpr size_t OFF_CLASSES = OFF_MASKS + (size_t)kP * kN;   // 51200256
static constexpr size_t OFF_BIAS    = OFF_CLASSES + 256;             // 51200512
static constexpr size_t OFF_PROBS   = OFF_BIAS + 3 * (size_t)kN;     // 51800512

// workspace layout (bytes)
static constexpr size_t WS_BITS       = 0;
static constexpr size_t WS_BITS_BYTES = (size_t)kP * kN / 8;         // 6,400,000
static constexpr size_t WS_COUNTS     = WS_BITS_BYTES;               // int[256]
static constexpr size_t WS_SCORE      = WS_COUNTS + 1024;            // float[256]
static constexpr size_t WS_REP        = WS_SCORE + 1024;             // int[256], init 0x7f
static constexpr size_t WS_CLS        = WS_REP + 1024;               // int[256]
static constexpr size_t WS_FLAG       = WS_CLS + 1024;               // float[256]
static constexpr size_t WS_SEG        = WS_FLAG + 1024;              // int[kN]

// K1: softmax + argmax per point; write probs; copy bias through.
__global__ void k_softmax(const float* __restrict__ logit,
                          const float* __restrict__ bias,
                          float* __restrict__ out,
                          int* __restrict__ seg) {
    int tid = blockIdx.x * blockDim.x + threadIdx.x;
    // bias passthrough: 600000 floats = 150000 float4
    if (tid < 150000) {
        const float4* b4 = (const float4*)bias;
        float4*       o4 = (float4*)(out + OFF_BIAS);
        o4[tid] = b4[tid];
    }
    if (tid >= kN) return;

    const float4* l4 = (const float4*)(logit + (size_t)tid * kC);
    float v[kC];
#pragma unroll
    for (int c = 0; c < 5; c++) {
        float4 t = l4[c];
        v[4*c] = t.x; v[4*c+1] = t.y; v[4*c+2] = t.z; v[4*c+3] = t.w;
    }
    float m = v[0]; int arg = 0;
#pragma unroll
    for (int i = 1; i < kC; i++) if (v[i] > m) { m = v[i]; arg = i; }   // first max
    float s = 0.0f;
#pragma unroll
    for (int i = 0; i < kC; i++) { v[i] = __expf(v[i] - m); s += v[i]; }
    float inv = 1.0f / s;
    float4* p4 = (float4*)(out + OFF_PROBS + (size_t)tid * kC);
#pragma unroll
    for (int c = 0; c < 5; c++) {
        float4 t;
        t.x = v[4*c] * inv; t.y = v[4*c+1] * inv;
        t.z = v[4*c+2] * inv; t.w = v[4*c+3] * inv;
        p4[c] = t;
    }
    seg[tid] = arg;
}

// K2: scatter pairs -> dedupe bit array, unique counts, segment-min rep.
__global__ void k_scatter(const int* __restrict__ prop,
                          const int* __restrict__ pt,
                          unsigned int* __restrict__ bits,
                          int* __restrict__ counts,
                          int* __restrict__ rep) {
    __shared__ int s_cnt[kP];
    __shared__ int s_rep[kP];
    int t = threadIdx.x;
    if (t < kP) { s_cnt[t] = 0; s_rep[t] = 0x7fffffff; }
    __syncthreads();
    int base = blockIdx.x * (blockDim.x * 4);
#pragma unroll
    for (int it = 0; it < 4; it++) {
        int idx = base + it * blockDim.x + t;
        if (idx < kM) {
            int p = prop[idx];
            int n = pt[idx];
            unsigned int bitpos = (unsigned int)p * (unsigned int)kN + (unsigned int)n;
            unsigned int w = bitpos >> 5;
            unsigned int b = 1u << (bitpos & 31);
            unsigned int old = atomicOr(&bits[w], b);
            if (!(old & b)) atomicAdd(&s_cnt[p], 1);   // unique-pair count
            atomicMin(&s_rep[p], n);
        }
    }
    __syncthreads();
    if (t < kP) {
        if (s_cnt[t]) atomicAdd(&counts[t], s_cnt[t]);
        if (s_rep[t] != 0x7fffffff) atomicMin(&rep[t], s_rep[t]);
    }
}

// K3: per-proposal class + flag; write pred_classes.
__global__ void k_finalize_cls(const int* __restrict__ counts,
                               const int* __restrict__ rep,
                               const int* __restrict__ seg,
                               int* __restrict__ cls,
                               float* __restrict__ flagv,
                               float* __restrict__ out) {
    int p = threadIdx.x;
    int r = rep[p];                       // empty segment -> 0x7f7f7f7f, clip like jnp.clip
    r = r < 0 ? 0 : (r > kN - 1 ? kN - 1 : r);
    int c = seg[r];
    bool fl = counts[p] > kThreshPts;
    cls[p]  = c;
    flagv[p] = fl ? 1.0f : 0.0f;
    out[OFF_CLASSES + p] = fl ? (float)c : -1.0f;
}

// K4: expand bit array -> pred_masks (float 0/1 * flag), gather score_sum.
__global__ void k_masks(const unsigned int* __restrict__ bits,
                        const int* __restrict__ cls,
                        const float* __restrict__ flagv,
                        const float* __restrict__ probs,
                        float* __restrict__ masks,
                        float* __restrict__ score) {
    int f = blockIdx.x * 256 + threadIdx.x;          // float4 index, < P*N/4 = 12.8M
    unsigned int word = bits[f >> 3];
    unsigned int nib  = ((unsigned)f & 7u) * 4u;
    unsigned int b    = (word >> nib) & 0xFu;
    int p = (int)((unsigned)f / 50000u);             // N/4 floats4 per row
    float fv = flagv[p];
    float4 o;
    o.x = (b & 1u) ? fv : 0.0f;
    o.y = (b & 2u) ? fv : 0.0f;
    o.z = (b & 4u) ? fv : 0.0f;
    o.w = (b & 8u) ? fv : 0.0f;
    ((float4*)masks)[f] = o;

    float s = 0.0f;
    if (b) {
        int c  = cls[p];
        int n0 = f * 4 - p * kN;                     // point index of o.x
        if (b & 1u) s += probs[(size_t)(n0    ) * kC + c];
        if (b & 2u) s += probs[(size_t)(n0 + 1) * kC + c];
        if (b & 4u) s += probs[(size_t)(n0 + 2) * kC + c];
        if (b & 8u) s += probs[(size_t)(n0 + 3) * kC + c];
    }
    // reduce within wave when the whole wave is in one proposal row (common case)
    int p0  = __shfl(p, 0);
    int p63 = __shfl(p, 63);
    if (p0 == p63) {
        for (int off = 32; off; off >>= 1) s += __shfl_down(s, off);
        if ((threadIdx.x & 63) == 0 && s != 0.0f) atomicAdd(&score[p], s);
    } else {
        if (s != 0.0f) atomicAdd(&score[p], s);
    }
}

// K5: final scores.
__global__ void k_scores(const float* __restrict__ score,
                         const int* __restrict__ counts,
                         const float* __restrict__ flagv,
                         float* __restrict__ out) {
    int p = threadIdx.x;
    int cnt = counts[p];
    float denom = (float)(cnt > 1 ? cnt : 1);
    out[OFF_SCORES + p] = (flagv[p] != 0.0f) ? score[p] / denom : 0.0f;
}

extern "C" void kernel_launch(void* const* d_in, const int* in_sizes, int n_in,
                              void* d_out, int out_size, void* d_ws, size_t ws_size,
                              hipStream_t stream) {
    const float* logit = (const float*)d_in[0];
    const float* bias  = (const float*)d_in[1];
    // d_in[2] = coord: dead code in the reference (center_pred unused)
    const int* prop = (const int*)d_in[3];
    const int* pt   = (const int*)d_in[4];
    float* out = (float*)d_out;
    char*  ws  = (char*)d_ws;

    unsigned int* bits   = (unsigned int*)(ws + WS_BITS);
    int*          counts = (int*)(ws + WS_COUNTS);
    float*        score  = (float*)(ws + WS_SCORE);
    int*          rep    = (int*)(ws + WS_REP);
    int*          cls    = (int*)(ws + WS_CLS);
    float*        flagv  = (float*)(ws + WS_FLAG);
    int*          seg    = (int*)(ws + WS_SEG);

    // zero bits+counts+score in one memset; rep -> 0x7f7f7f7f (> any point id)
    hipMemsetAsync(ws, 0, WS_BITS_BYTES + 2048, stream);
    hipMemsetAsync(ws + WS_REP, 0x7f, 1024, stream);

    k_softmax<<<(kN + 255) / 256, 256, 0, stream>>>(logit, bias, out, seg);
    k_scatter<<<(kM + 4095) / 4096, 1024, 0, stream>>>(prop, pt, bits, counts, rep);
    k_finalize_cls<<<1, kP, 0, stream>>>(counts, rep, seg, cls, flagv, out);
    k_masks<<<(kP * kN / 4) / 256, 256, 0, stream>>>(bits, cls, flagv,
                                                     out + OFF_PROBS, out + OFF_MASKS, score);
    k_scores<<<1, kP, 0, stream>>>(score, counts, flagv, out);
}

// Round 2
// 290.830 us; speedup vs baseline: 3.0289x; 3.0289x over previous
//
#include <hip/hip_runtime.h>

static constexpr int    kN = 200000;
static constexpr int    kC = 20;
static constexpr int    kP = 256;
static constexpr int    kM = 400000;
static constexpr int    kThreshPts = 100;
static constexpr int    kWordsPerRow = kN / 32;                      // 6250

// output layout (float elements)
static constexpr size_t OFF_SCORES  = 0;
static constexpr size_t OFF_MASKS   = 256;
static constexpr size_t OFF_CLASSES = OFF_MASKS + (size_t)kP * kN;   // 51200256
static constexpr size_t OFF_BIAS    = OFF_CLASSES + 256;             // 51200512
static constexpr size_t OFF_PROBS   = OFF_BIAS + 3 * (size_t)kN;     // 51800512

// workspace layout (bytes)
static constexpr size_t WS_BITS       = 0;
static constexpr size_t WS_BITS_BYTES = (size_t)kP * kN / 8;         // 6,400,000
static constexpr size_t WS_COUNTS     = WS_BITS_BYTES;               // int[256]
static constexpr size_t WS_REP        = WS_COUNTS + 1024;            // int[256], init 0x7f
static constexpr size_t WS_CLS        = WS_REP + 1024;               // int[256]
static constexpr size_t WS_FLAG       = WS_CLS + 1024;               // float[256]
static constexpr size_t WS_SEG        = WS_FLAG + 1024;              // int[kN]

// K1: softmax + argmax per point; write probs; copy bias through.
__global__ void k_softmax(const float* __restrict__ logit,
                          const float* __restrict__ bias,
                          float* __restrict__ out,
                          int* __restrict__ seg) {
    int tid = blockIdx.x * blockDim.x + threadIdx.x;
    // bias passthrough: 600000 floats = 150000 float4
    if (tid < 150000) {
        const float4* b4 = (const float4*)bias;
        float4*       o4 = (float4*)(out + OFF_BIAS);
        o4[tid] = b4[tid];
    }
    if (tid >= kN) return;

    const float4* l4 = (const float4*)(logit + (size_t)tid * kC);
    float v[kC];
#pragma unroll
    for (int c = 0; c < 5; c++) {
        float4 t = l4[c];
        v[4*c] = t.x; v[4*c+1] = t.y; v[4*c+2] = t.z; v[4*c+3] = t.w;
    }
    float m = v[0]; int arg = 0;
#pragma unroll
    for (int i = 1; i < kC; i++) if (v[i] > m) { m = v[i]; arg = i; }   // first max
    float s = 0.0f;
#pragma unroll
    for (int i = 0; i < kC; i++) { v[i] = __expf(v[i] - m); s += v[i]; }
    float inv = 1.0f / s;
    float4* p4 = (float4*)(out + OFF_PROBS + (size_t)tid * kC);
#pragma unroll
    for (int c = 0; c < 5; c++) {
        float4 t;
        t.x = v[4*c] * inv; t.y = v[4*c+1] * inv;
        t.z = v[4*c+2] * inv; t.w = v[4*c+3] * inv;
        p4[c] = t;
    }
    seg[tid] = arg;
}

// K2: scatter pairs -> dedupe bit array, unique counts, segment-min rep.
__global__ void k_scatter(const int* __restrict__ prop,
                          const int* __restrict__ pt,
                          unsigned int* __restrict__ bits,
                          int* __restrict__ counts,
                          int* __restrict__ rep) {
    __shared__ int s_cnt[kP];
    __shared__ int s_rep[kP];
    int t = threadIdx.x;
    if (t < kP) { s_cnt[t] = 0; s_rep[t] = 0x7fffffff; }
    __syncthreads();
    int base = blockIdx.x * (blockDim.x * 4);
#pragma unroll
    for (int it = 0; it < 4; it++) {
        int idx = base + it * blockDim.x + t;
        if (idx < kM) {
            int p = prop[idx];
            int n = pt[idx];
            unsigned int bitpos = (unsigned int)p * (unsigned int)kN + (unsigned int)n;
            unsigned int w = bitpos >> 5;
            unsigned int b = 1u << (bitpos & 31);
            unsigned int old = atomicOr(&bits[w], b);
            if (!(old & b)) atomicAdd(&s_cnt[p], 1);   // unique-pair count
            atomicMin(&s_rep[p], n);
        }
    }
    __syncthreads();
    if (t < kP) {
        if (s_cnt[t]) atomicAdd(&counts[t], s_cnt[t]);
        if (s_rep[t] != 0x7fffffff) atomicMin(&rep[t], s_rep[t]);
    }
}

// K3: per-proposal class + flag; write pred_classes.
__global__ void k_finalize_cls(const int* __restrict__ counts,
                               const int* __restrict__ rep,
                               const int* __restrict__ seg,
                               int* __restrict__ cls,
                               float* __restrict__ flagv,
                               float* __restrict__ out) {
    int p = threadIdx.x;
    int r = rep[p];                       // empty segment -> 0x7f7f7f7f, clip like jnp.clip
    r = r < 0 ? 0 : (r > kN - 1 ? kN - 1 : r);
    int c = seg[r];
    bool fl = counts[p] > kThreshPts;
    cls[p]  = c;
    flagv[p] = fl ? 1.0f : 0.0f;
    out[OFF_CLASSES + p] = fl ? (float)c : -1.0f;
}

// K4: pure expansion: bit array -> pred_masks (0/flag). No atomics, no gathers.
__global__ void k_masks(const unsigned int* __restrict__ bits,
                        const float* __restrict__ flagv,
                        float* __restrict__ masks) {
    int f = blockIdx.x * 256 + threadIdx.x;          // float4 index, < P*N/4 = 12.8M
    unsigned int word = bits[f >> 3];
    unsigned int nib  = ((unsigned)f & 7u) * 4u;
    unsigned int b    = (word >> nib) & 0xFu;
    int p = (int)((unsigned)f / 50000u);             // N/4 float4s per row
    float fv = flagv[p];
    float4 o;
    o.x = (b & 1u) ? fv : 0.0f;
    o.y = (b & 2u) ? fv : 0.0f;
    o.z = (b & 4u) ? fv : 0.0f;
    o.w = (b & 8u) ? fv : 0.0f;
    ((float4*)masks)[f] = o;
}

// K5: one block per proposal — scan bit row, gather probs, reduce, final score.
__global__ void k_score_rows(const unsigned int* __restrict__ bits,
                             const int* __restrict__ cls,
                             const int* __restrict__ counts,
                             const float* __restrict__ flagv,
                             const float* __restrict__ probs,
                             float* __restrict__ out) {
    int p = blockIdx.x;
    int c = cls[p];
    const unsigned int* row = bits + (size_t)p * kWordsPerRow;
    float s = 0.0f;
    for (int w = threadIdx.x; w < kWordsPerRow; w += 256) {
        unsigned int word = row[w];
        while (word) {
            int b = __ffs(word) - 1;
            int n = w * 32 + b;
            s += probs[(size_t)n * kC + c];
            word &= word - 1;
        }
    }
    __shared__ float red[4];
    for (int off = 32; off; off >>= 1) s += __shfl_down(s, off);
    if ((threadIdx.x & 63) == 0) red[threadIdx.x >> 6] = s;
    __syncthreads();
    if (threadIdx.x == 0) {
        float tot = red[0] + red[1] + red[2] + red[3];
        int cnt = counts[p];
        float denom = (float)(cnt > 1 ? cnt : 1);
        out[OFF_SCORES + p] = (flagv[p] != 0.0f) ? tot / denom : 0.0f;
    }
}

extern "C" void kernel_launch(void* const* d_in, const int* in_sizes, int n_in,
                              void* d_out, int out_size, void* d_ws, size_t ws_size,
                              hipStream_t stream) {
    const float* logit = (const float*)d_in[0];
    const float* bias  = (const float*)d_in[1];
    // d_in[2] = coord: dead code in the reference (center_pred unused)
    const int* prop = (const int*)d_in[3];
    const int* pt   = (const int*)d_in[4];
    float* out = (float*)d_out;
    char*  ws  = (char*)d_ws;

    unsigned int* bits   = (unsigned int*)(ws + WS_BITS);
    int*          counts = (int*)(ws + WS_COUNTS);
    int*          rep    = (int*)(ws + WS_REP);
    int*          cls    = (int*)(ws + WS_CLS);
    float*        flagv  = (float*)(ws + WS_FLAG);
    int*          seg    = (int*)(ws + WS_SEG);

    // zero bits+counts in one memset; rep -> 0x7f7f7f7f (> any point id)
    hipMemsetAsync(ws, 0, WS_BITS_BYTES + 1024, stream);
    hipMemsetAsync(ws + WS_REP, 0x7f, 1024, stream);

    k_softmax<<<(kN + 255) / 256, 256, 0, stream>>>(logit, bias, out, seg);
    k_scatter<<<(kM + 4095) / 4096, 1024, 0, stream>>>(prop, pt, bits, counts, rep);
    k_finalize_cls<<<1, kP, 0, stream>>>(counts, rep, seg, cls, flagv, out);
    k_masks<<<(kP * kN / 4) / 256, 256, 0, stream>>>(bits, flagv, out + OFF_MASKS);
    k_score_rows<<<kP, 256, 0, stream>>>(bits, cls, counts, flagv,
                                         out + OFF_PROBS, out);
}

// Round 4
// 278.089 us; speedup vs baseline: 3.1676x; 1.0458x over previous
//
#include <hip/hip_runtime.h>

static constexpr int    kN = 200000;
static constexpr int    kC = 20;
static constexpr int    kP = 256;
static constexpr int    kM = 400000;
static constexpr int    kThreshPts = 100;
static constexpr int    kWordsPerRow = kN / 32;                      // 6250
static constexpr int    kBlocksPerRowScore = 8;
static constexpr int    kWordsPerScoreBlock = (kWordsPerRow + kBlocksPerRowScore - 1) / kBlocksPerRowScore; // 782

typedef float nfloat4 __attribute__((ext_vector_type(4)));           // native vec for nontemporal builtin

// output layout (float elements)
static constexpr size_t OFF_SCORES  = 0;
static constexpr size_t OFF_MASKS   = 256;
static constexpr size_t OFF_CLASSES = OFF_MASKS + (size_t)kP * kN;   // 51200256
static constexpr size_t OFF_BIAS    = OFF_CLASSES + 256;             // 51200512
static constexpr size_t OFF_PROBS   = OFF_BIAS + 3 * (size_t)kN;     // 51800512

// workspace layout (bytes)
static constexpr size_t WS_BITS       = 0;
static constexpr size_t WS_BITS_BYTES = (size_t)kP * kN / 8;         // 6,400,000
static constexpr size_t WS_COUNTS     = WS_BITS_BYTES;               // int[256]
static constexpr size_t WS_REP        = WS_COUNTS + 1024;            // int[256]
static constexpr size_t WS_CLS        = WS_REP + 1024;               // int[256]
static constexpr size_t WS_FLAG       = WS_CLS + 1024;               // float[256]
static constexpr size_t WS_SCORE      = WS_FLAG + 1024;              // float[256]
static constexpr size_t WS_SEG        = WS_SCORE + 1024;             // int[kN]

// K1: softmax + argmax per point; write probs; copy bias; zero/init workspace.
__global__ void k_softmax(const float* __restrict__ logit,
                          const float* __restrict__ bias,
                          float* __restrict__ out,
                          int* __restrict__ seg,
                          uint4* __restrict__ bits4,
                          int* __restrict__ rep,
                          float* __restrict__ score) {
    int tid = blockIdx.x * blockDim.x + threadIdx.x;

    // zero the 6.4 MB bit array: 400000 uint4, 2 per thread for tid < 200000
    if (tid < kN) {
        uint4 z = make_uint4(0, 0, 0, 0);
        bits4[2 * tid]     = z;
        bits4[2 * tid + 1] = z;
    }
    if (blockIdx.x == 0 && threadIdx.x < kP) {
        rep[threadIdx.x]   = 0x7fffffff;   // > any point id; matches segment_min empty + clip
        score[threadIdx.x] = 0.0f;
    }

    // bias passthrough: 600000 floats = 150000 float4
    if (tid < 150000) {
        const float4* b4 = (const float4*)bias;
        float4*       o4 = (float4*)(out + OFF_BIAS);
        o4[tid] = b4[tid];
    }
    if (tid >= kN) return;

    const float4* l4 = (const float4*)(logit + (size_t)tid * kC);
    float v[kC];
#pragma unroll
    for (int c = 0; c < 5; c++) {
        float4 t = l4[c];
        v[4*c] = t.x; v[4*c+1] = t.y; v[4*c+2] = t.z; v[4*c+3] = t.w;
    }
    float m = v[0]; int arg = 0;
#pragma unroll
    for (int i = 1; i < kC; i++) if (v[i] > m) { m = v[i]; arg = i; }   // first max, like argmax
    float s = 0.0f;
#pragma unroll
    for (int i = 0; i < kC; i++) { v[i] = __expf(v[i] - m); s += v[i]; }
    float inv = 1.0f / s;
    float4* p4 = (float4*)(out + OFF_PROBS + (size_t)tid * kC);
#pragma unroll
    for (int c = 0; c < 5; c++) {
        float4 t;
        t.x = v[4*c] * inv; t.y = v[4*c+1] * inv;
        t.z = v[4*c+2] * inv; t.w = v[4*c+3] * inv;
        p4[c] = t;
    }
    seg[tid] = arg;
}

// K2: scatter pairs -> bit array (fire-and-forget) + segment-min rep.
__global__ void k_scatter(const int* __restrict__ prop,
                          const int* __restrict__ pt,
                          unsigned int* __restrict__ bits,
                          int* __restrict__ rep) {
    __shared__ int s_rep[kP];
    int t = threadIdx.x;
    if (t < kP) s_rep[t] = 0x7fffffff;
    __syncthreads();
    int base = blockIdx.x * (blockDim.x * 4);
#pragma unroll
    for (int it = 0; it < 4; it++) {
        int idx = base + it * blockDim.x + t;
        if (idx < kM) {
            int p = prop[idx];
            int n = pt[idx];
            unsigned int bitpos = (unsigned int)p * (unsigned int)kN + (unsigned int)n;
            atomicOr(&bits[bitpos >> 5], 1u << (bitpos & 31));   // no return -> no vmcnt stall
            atomicMin(&s_rep[p], n);
        }
    }
    __syncthreads();
    if (t < kP && s_rep[t] != 0x7fffffff) atomicMin(&rep[t], s_rep[t]);
}

// K3: one block per proposal — popcount row (= unique count), class, flag.
__global__ void k_count_cls(const unsigned int* __restrict__ bits,
                            const int* __restrict__ rep,
                            const int* __restrict__ seg,
                            int* __restrict__ counts,
                            int* __restrict__ cls,
                            float* __restrict__ flagv,
                            float* __restrict__ out) {
    int p = blockIdx.x;
    const uint2* row2 = (const uint2*)(bits + (size_t)p * kWordsPerRow);  // 3125 uint2
    int cnt = 0;
    for (int i = threadIdx.x; i < kWordsPerRow / 2; i += 256) {
        uint2 w = row2[i];
        cnt += __popc(w.x) + __popc(w.y);
    }
    __shared__ int red[4];
    for (int off = 32; off; off >>= 1) cnt += __shfl_down(cnt, off);
    if ((threadIdx.x & 63) == 0) red[threadIdx.x >> 6] = cnt;
    __syncthreads();
    if (threadIdx.x == 0) {
        int tot = red[0] + red[1] + red[2] + red[3];
        int r = rep[p];
        r = r < 0 ? 0 : (r > kN - 1 ? kN - 1 : r);
        int c = seg[r];
        bool fl = tot > kThreshPts;
        counts[p] = tot;
        cls[p]    = c;
        flagv[p]  = fl ? 1.0f : 0.0f;
        out[OFF_CLASSES + p] = fl ? (float)c : -1.0f;
    }
}

// K4: pure expansion: bit array -> pred_masks (0/flag). Non-temporal stores.
__global__ void k_masks(const unsigned int* __restrict__ bits,
                        const float* __restrict__ flagv,
                        float* __restrict__ masks) {
    int f = blockIdx.x * 256 + threadIdx.x;          // float4 index, < P*N/4 = 12.8M
    unsigned int word = bits[f >> 3];
    unsigned int nib  = ((unsigned)f & 7u) * 4u;
    unsigned int b    = (word >> nib) & 0xFu;
    int p = (int)((unsigned)f / 50000u);             // N/4 float4s per row
    float fv = flagv[p];
    nfloat4 o;
    o.x = (b & 1u) ? fv : 0.0f;
    o.y = (b & 2u) ? fv : 0.0f;
    o.z = (b & 4u) ? fv : 0.0f;
    o.w = (b & 8u) ? fv : 0.0f;
    __builtin_nontemporal_store(o, &((nfloat4*)masks)[f]);
}

// K5: 8 blocks per proposal — scan bit-row slice, gather probs, block partial.
__global__ void k_score_part(const unsigned int* __restrict__ bits,
                             const int* __restrict__ cls,
                             const float* __restrict__ probs,
                             float* __restrict__ score) {
    int p = blockIdx.x >> 3;
    int q = blockIdx.x & 7;
    int c = cls[p];
    const unsigned int* row = bits + (size_t)p * kWordsPerRow;
    int wstart = q * kWordsPerScoreBlock;
    int wend   = wstart + kWordsPerScoreBlock;
    if (wend > kWordsPerRow) wend = kWordsPerRow;
    float s = 0.0f;
    for (int w = wstart + threadIdx.x; w < wend; w += 256) {
        unsigned int word = row[w];
        while (word) {
            int b = __ffs(word) - 1;
            int n = w * 32 + b;
            s += probs[(size_t)n * kC + c];
            word &= word - 1;
        }
    }
    __shared__ float red[4];
    for (int off = 32; off; off >>= 1) s += __shfl_down(s, off);
    if ((threadIdx.x & 63) == 0) red[threadIdx.x >> 6] = s;
    __syncthreads();
    if (threadIdx.x == 0) {
        float tot = red[0] + red[1] + red[2] + red[3];
        if (tot != 0.0f) atomicAdd(&score[p], tot);   // 2048 atomics total
    }
}

// K6: final scores.
__global__ void k_scores(const float* __restrict__ score,
                         const int* __restrict__ counts,
                         const float* __restrict__ flagv,
                         float* __restrict__ out) {
    int p = threadIdx.x;
    int cnt = counts[p];
    float denom = (float)(cnt > 1 ? cnt : 1);
    out[OFF_SCORES + p] = (flagv[p] != 0.0f) ? score[p] / denom : 0.0f;
}

extern "C" void kernel_launch(void* const* d_in, const int* in_sizes, int n_in,
                              void* d_out, int out_size, void* d_ws, size_t ws_size,
                              hipStream_t stream) {
    const float* logit = (const float*)d_in[0];
    const float* bias  = (const float*)d_in[1];
    // d_in[2] = coord: dead code in the reference (center_pred unused)
    const int* prop = (const int*)d_in[3];
    const int* pt   = (const int*)d_in[4];
    float* out = (float*)d_out;
    char*  ws  = (char*)d_ws;

    unsigned int* bits   = (unsigned int*)(ws + WS_BITS);
    int*          counts = (int*)(ws + WS_COUNTS);
    int*          rep    = (int*)(ws + WS_REP);
    int*          cls    = (int*)(ws + WS_CLS);
    float*        flagv  = (float*)(ws + WS_FLAG);
    float*        score  = (float*)(ws + WS_SCORE);
    int*          seg    = (int*)(ws + WS_SEG);

    k_softmax<<<(kN + 255) / 256, 256, 0, stream>>>(logit, bias, out, seg,
                                                    (uint4*)bits, rep, score);
    k_scatter<<<(kM + 4095) / 4096, 1024, 0, stream>>>(prop, pt, bits, rep);
    k_count_cls<<<kP, 256, 0, stream>>>(bits, rep, seg, counts, cls, flagv, out);
    k_masks<<<(kP * kN / 4) / 256, 256, 0, stream>>>(bits, flagv, out + OFF_MASKS);
    k_score_part<<<kP * kBlocksPerRowScore, 256, 0, stream>>>(bits, cls,
                                                              out + OFF_PROBS, score);
    k_scores<<<1, kP, 0, stream>>>(score, counts, flagv, out);
}